// Round 3
// baseline (18.171 us; speedup 1.0000x reference)
//
#include <hip/hip_runtime.h>

#define HALF_DT 0.005f   // DT/2, DT = 0.01

typedef __attribute__((ext_vector_type(8))) short short8;   // 8 x bf16 (4 VGPRs)
typedef __attribute__((ext_vector_type(4))) float f32x4;    // MFMA accumulator

// fp32 -> bf16 round-to-nearest-even
static __device__ inline short f2bf(float f) {
    union { float f; unsigned u; } x; x.f = f;
    unsigned r = (x.u + 0x7fffu + ((x.u >> 16) & 1u)) >> 16;
    return (short)r;
}

// load 8 consecutive fp32 (32B, 16B-aligned) -> bf16x8 fragment
static __device__ inline short8 cvt8(const float* __restrict__ p) {
    float4 lo = *reinterpret_cast<const float4*>(p);
    float4 hi = *reinterpret_cast<const float4*>(p + 4);
    short8 r;
    r[0] = f2bf(lo.x); r[1] = f2bf(lo.y); r[2] = f2bf(lo.z); r[3] = f2bf(lo.w);
    r[4] = f2bf(hi.x); r[5] = f2bf(hi.y); r[6] = f2bf(hi.z); r[7] = f2bf(hi.w);
    return r;
}

// ---------------------------------------------------------------------------
// Fully fused: per block of 32 output cols [C0, C0+31]:
//  Phase A (waves 0-5): v-slice via bf16 MFMA. p[i] = HALF_DT*tanh(z0.W[i]+b[i])
//      for i in [C0-8, C0+39] (3 col-tiles x 2 batch-halves = 6 chains, one
//      full-K chain per wave; fragment mapping identical to the verified
//      round-2 kernel). p=0 outside [0,2046].
//      wave 6: stage h halo tile [C0-4, C0+35] (0-padded) -> h_lds[32][40].
//      wave 7: zero scratch edges.
//  Phase B: x = h - 2Nh + 2N^2h - 2N^3h, N tridiag: (Nu)[i] = p[i-1]u[i-1]
//      - p[i]u[i+1]. Truncation err <= 2*0.01^4*|h| ~ 1e-7 (threshold 8.9e-2).
//      Three LDS passes over local cols c in [1,38] (i = C0-4+c); pollution
//      from uncomputed edges reaches only c<=3 / c>=36; outputs use c in [4,35].
// ---------------------------------------------------------------------------
__global__ __launch_bounds__(512) void fused_tcrs_kernel(
    const float* __restrict__ z0,    // (32, 512)
    const float* __restrict__ h,     // (32, 2048)
    const float* __restrict__ W,     // (2047, 512)
    const float* __restrict__ bias,  // (2047,)
    float* __restrict__ out)         // (32, 2048)
{
    __shared__ float p_lds[32][48];  // p[i], pc = i - (C0-8)
    __shared__ float h_lds[32][40];  // h[i], c  = i - (C0-4)
    __shared__ float ua[32][40];
    __shared__ float ub[32][40];

    const int tid  = threadIdx.x;
    const int wave = tid >> 6;
    const int lane = tid & 63;
    const int C0    = blockIdx.x * 32;
    const int vbase = C0 - 8;
    const int hbase = C0 - 4;

    if (wave < 6) {
        const int t    = wave % 3;           // col tile 0..2
        const int half = wave / 3;           // batch half 0..1
        const int m    = lane & 15;
        const int q    = lane >> 4;
        const int vcol = vbase + t * 16 + m;
        const int wrow = min(max(vcol, 0), 2046);   // clamp load row
        const bool valid = (vcol >= 0) && (vcol < 2047);

        // A-frag: lane holds z0[half*16+m][k=8q+j]; B-frag: W[vcol][k] (=B[k][n=m])
        const float* zA = z0 + (half * 16 + m) * 512 + 8 * q;
        const float* wB = W + wrow * 512 + 8 * q;

        f32x4 acc = {0.f, 0.f, 0.f, 0.f};
        #pragma unroll 4
        for (int k0 = 0; k0 < 512; k0 += 32) {
            short8 a = cvt8(zA + k0);
            short8 b = cvt8(wB + k0);
            acc = __builtin_amdgcn_mfma_f32_16x16x32_bf16(a, b, acc, 0, 0, 0);
        }

        // D: row = 4q + r (batch within half), col = m
        const float bv = valid ? bias[vcol] : 0.f;
        #pragma unroll
        for (int r = 0; r < 4; ++r) {
            const int b = half * 16 + 4 * q + r;
            p_lds[b][t * 16 + m] = valid ? HALF_DT * tanhf(acc[r] + bv) : 0.f;
        }
    } else if (wave == 6) {
        // h halo tile: 32 batches x 10 float4 (40 cols from hbase), 0-padded
        for (int it = lane; it < 320; it += 64) {
            const int b = it / 10, j = it % 10;
            const int f = (hbase >> 2) + j;      // float4 index within h row
            float4 val = make_float4(0.f, 0.f, 0.f, 0.f);
            if (f >= 0 && f < 512)
                val = reinterpret_cast<const float4*>(h + b * 2048)[f];
            *reinterpret_cast<float4*>(&h_lds[b][j * 4]) = val;
        }
    } else {
        // wave 7: zero scratch edges (c=0,39 never computed; read by next pass)
        if (lane < 32) {
            ua[lane][0] = 0.f; ua[lane][39] = 0.f;
            ub[lane][0] = 0.f; ub[lane][39] = 0.f;
        }
    }
    __syncthreads();

    // Phase B: three tridiagonal applications. 32 b x 38 c = 1216 items.
    float accv[3];
    // pass 1: u1 = N h
    #pragma unroll
    for (int k = 0; k < 3; ++k) {
        const int idx = tid + k * 512;
        accv[k] = 0.f;
        if (idx < 1216) {
            const int b = idx / 38, c = idx % 38 + 1;
            const float u1 = p_lds[b][c + 3] * h_lds[b][c - 1]
                           - p_lds[b][c + 4] * h_lds[b][c + 1];
            ua[b][c] = u1;
            accv[k] = -2.f * u1;
        }
    }
    __syncthreads();
    // pass 2: u2 = N u1
    #pragma unroll
    for (int k = 0; k < 3; ++k) {
        const int idx = tid + k * 512;
        if (idx < 1216) {
            const int b = idx / 38, c = idx % 38 + 1;
            const float u2 = p_lds[b][c + 3] * ua[b][c - 1]
                           - p_lds[b][c + 4] * ua[b][c + 1];
            ub[b][c] = u2;
            accv[k] += 2.f * u2;
        }
    }
    __syncthreads();
    // pass 3: u3 = N u2; x = h + (-2u1 + 2u2 - 2u3); store cols c in [4,35]
    #pragma unroll
    for (int k = 0; k < 3; ++k) {
        const int idx = tid + k * 512;
        if (idx < 1216) {
            const int b = idx / 38, c = idx % 38 + 1;
            const float u3 = p_lds[b][c + 3] * ub[b][c - 1]
                           - p_lds[b][c + 4] * ub[b][c + 1];
            const float x = h_lds[b][c] + accv[k] - 2.f * u3;
            if (c >= 4 && c <= 35)
                out[b * 2048 + C0 + (c - 4)] = x;
        }
    }
}

extern "C" void kernel_launch(void* const* d_in, const int* in_sizes, int n_in,
                              void* d_out, int out_size, void* d_ws, size_t ws_size,
                              hipStream_t stream) {
    const float* z0   = (const float*)d_in[0];   // (32, 512)
    const float* h    = (const float*)d_in[1];   // (32, 2048)
    const float* W    = (const float*)d_in[2];   // (2047, 512)
    const float* bias = (const float*)d_in[3];   // (2047,)
    float* out = (float*)d_out;                  // (32, 2048)

    fused_tcrs_kernel<<<64, 512, 0, stream>>>(z0, h, W, bias, out);
}

// Round 4
// 14.948 us; speedup vs baseline: 1.2156x; 1.2156x over previous
//
#include <hip/hip_runtime.h>
#include <hip/hip_bf16.h>

#define HALF_DT 0.005f   // DT/2, DT = 0.01

typedef __attribute__((ext_vector_type(8))) short short8;   // 8 x bf16 (4 VGPRs)
typedef __attribute__((ext_vector_type(4))) float f32x4;    // MFMA accumulator

// fp32 -> bf16 via hardware cvt (compiler fuses pairs into v_cvt_pk_bf16_f32)
static __device__ inline short f2bf(float f) {
    __hip_bfloat16 b = __float2bfloat16(f);
    union { __hip_bfloat16 b; short s; } u; u.b = b;
    return u.s;
}

// load 8 consecutive fp32 (32B, 16B-aligned) -> bf16x8 fragment
static __device__ inline short8 cvt8(const float* __restrict__ p) {
    float4 lo = *reinterpret_cast<const float4*>(p);
    float4 hi = *reinterpret_cast<const float4*>(p + 4);
    short8 r;
    r[0] = f2bf(lo.x); r[1] = f2bf(lo.y); r[2] = f2bf(lo.z); r[3] = f2bf(lo.w);
    r[4] = f2bf(hi.x); r[5] = f2bf(hi.y); r[6] = f2bf(hi.z); r[7] = f2bf(hi.w);
    return r;
}

// ---------------------------------------------------------------------------
// Kernel 1: v[b][col] = tanh(z0[b,:] . W[col,:] + bias[col]) via bf16 MFMA.
// 128 blocks x 128 threads (2 waves). Wave w handles batch half w (16 rows),
// same 16 cols -> W fetched once per block from HBM (2nd wave hits L1).
// One MFMA chain per wave, K=512 in 16 steps.
// Fragment mapping (verified round 2): A lane l holds z0[half*16+(l&15)][8*(l>>4)+j];
// B lane l holds W[col0+(l&15)][8*(l>>4)+j]; D lane l reg r -> batch 4*(l>>4)+r,
// col = col0 + (l&15). Output v_ws[b][2048]; col 2047 never written (K2 zeros it).
// ---------------------------------------------------------------------------
__global__ __launch_bounds__(128) void v_mfma_kernel(
    const float* __restrict__ z0,    // (32, 512)
    const float* __restrict__ W,     // (2047, 512)
    const float* __restrict__ bias,  // (2047,)
    float* __restrict__ v_ws)        // (32, 2048)
{
    const int tid  = threadIdx.x;
    const int half = tid >> 6;           // batch half 0/1
    const int lane = tid & 63;
    const int m    = lane & 15;
    const int q    = lane >> 4;          // 0..3
    const int col  = blockIdx.x * 16 + m;
    const int wcol = (col < 2046) ? col : 2046;   // clamp load row (store guarded)

    const float* zA = z0 + (half * 16 + m) * 512 + 8 * q;
    const float* wB = W + wcol * 512 + 8 * q;

    f32x4 acc = {0.f, 0.f, 0.f, 0.f};
    #pragma unroll 4
    for (int k0 = 0; k0 < 512; k0 += 32) {
        short8 a = cvt8(zA + k0);
        short8 b = cvt8(wB + k0);
        acc = __builtin_amdgcn_mfma_f32_16x16x32_bf16(a, b, acc, 0, 0, 0);
    }

    if (col < 2047) {
        const float bv = bias[col];
        #pragma unroll
        for (int r = 0; r < 4; ++r) {
            const int b = half * 16 + 4 * q + r;
            v_ws[b * 2048 + col] = tanhf(acc[r] + bv);
        }
    }
}

// ---------------------------------------------------------------------------
// Kernel 2: x = h - 2*N h + 2*N^2 h - 2*N^3 h  (truncated Neumann for
//   (I+N)x = (I-N)h, ||N||inf <= 0.01, truncation err ~1e-7; threshold 8.9e-2).
// (N u)[i] = p[i-1]*u[i-1] - p[i]*u[i+1], p[i] = HALF_DT*v[i] (p=0 outside
// [0,2046] -- zero-padding enforces both physical boundaries exactly).
// Grid: 64 blocks = (batch b) x (column half). Each block covers output cols
// [cbase, cbase+1023] with halo +-4; float4 staging; 3 barriers.
// ---------------------------------------------------------------------------
__global__ __launch_bounds__(256) void solve3_kernel(
    const float* __restrict__ h,
    const float* __restrict__ v_ws,
    float* __restrict__ out)
{
    __shared__ float hl [1032];   // h[g(c)], g(c) = cbase - 4 + c
    __shared__ float p_l[1032];   // HALF_DT * v[g(c)], 0 out of range
    __shared__ float u1l[1032];
    __shared__ float u2l[1032];

    const int b     = blockIdx.x >> 1;
    const int cbase = (blockIdx.x & 1) * 1024;
    const int tid   = threadIdx.x;

    // stage: 258 float4 quads; quad validity is all-or-nothing except the
    // single quad containing global col 2047 (v slot uninitialized -> force 0)
    for (int j = tid; j < 258; j += 256) {
        const int i0 = cbase - 4 + 4 * j;
        float4 hv = make_float4(0.f, 0.f, 0.f, 0.f);
        float4 vv = make_float4(0.f, 0.f, 0.f, 0.f);
        if (i0 >= 0 && i0 + 3 < 2048) {
            hv = *reinterpret_cast<const float4*>(h    + b * 2048 + i0);
            vv = *reinterpret_cast<const float4*>(v_ws + b * 2048 + i0);
            if (i0 + 3 == 2047) vv.w = 0.f;   // p[2047] does not exist
        }
        *reinterpret_cast<float4*>(&hl[4 * j]) = hv;
        vv.x *= HALF_DT; vv.y *= HALF_DT; vv.z *= HALF_DT; vv.w *= HALF_DT;
        *reinterpret_cast<float4*>(&p_l[4 * j]) = vv;
    }
    __syncthreads();

    // pass 1: u1 = N h on c in [2, 1029]
    for (int c = 2 + tid; c <= 1029; c += 256)
        u1l[c] = p_l[c - 1] * hl[c - 1] - p_l[c] * hl[c + 1];
    __syncthreads();

    // pass 2: u2 = N u1 on c in [3, 1028]
    for (int c = 3 + tid; c <= 1028; c += 256)
        u2l[c] = p_l[c - 1] * u1l[c - 1] - p_l[c] * u1l[c + 1];
    __syncthreads();

    // pass 3: u3 = N u2; x = h - 2*(u1 - u2 + u3); store c in [4, 1027]
    for (int c = 4 + tid; c <= 1027; c += 256) {
        const float u3 = p_l[c - 1] * u2l[c - 1] - p_l[c] * u2l[c + 1];
        out[b * 2048 + cbase + (c - 4)] = hl[c] - 2.f * (u1l[c] - u2l[c] + u3);
    }
}

extern "C" void kernel_launch(void* const* d_in, const int* in_sizes, int n_in,
                              void* d_out, int out_size, void* d_ws, size_t ws_size,
                              hipStream_t stream) {
    const float* z0   = (const float*)d_in[0];   // (32, 512)
    const float* h    = (const float*)d_in[1];   // (32, 2048)
    const float* W    = (const float*)d_in[2];   // (2047, 512)
    const float* bias = (const float*)d_in[3];   // (2047,)
    float* out  = (float*)d_out;                 // (32, 2048)
    float* v_ws = (float*)d_ws;                  // (32, 2048) floats = 256 KB

    v_mfma_kernel<<<128, 128, 0, stream>>>(z0, W, bias, v_ws);
    solve3_kernel<<<64, 256, 0, stream>>>(h, v_ws, out);
}

// Round 5
// 12.504 us; speedup vs baseline: 1.4532x; 1.1954x over previous
//
#include <hip/hip_runtime.h>
#include <hip/hip_bf16.h>

#define HALF_DT 0.005f   // DT/2, DT = 0.01

typedef __attribute__((ext_vector_type(8))) short short8;   // 8 x bf16 (4 VGPRs)
typedef __attribute__((ext_vector_type(4))) float f32x4;    // MFMA accumulator

// fp32 -> bf16 via hardware cvt (compiler fuses pairs into v_cvt_pk_bf16_f32)
static __device__ inline short f2bf(float f) {
    __hip_bfloat16 b = __float2bfloat16(f);
    union { __hip_bfloat16 b; short s; } u; u.b = b;
    return u.s;
}

// load 8 consecutive fp32 (32B, 16B-aligned) -> bf16x8 fragment
static __device__ inline short8 cvt8(const float* __restrict__ p) {
    float4 lo = *reinterpret_cast<const float4*>(p);
    float4 hi = *reinterpret_cast<const float4*>(p + 4);
    short8 r;
    r[0] = f2bf(lo.x); r[1] = f2bf(lo.y); r[2] = f2bf(lo.z); r[3] = f2bf(lo.w);
    r[4] = f2bf(hi.x); r[5] = f2bf(hi.y); r[6] = f2bf(hi.z); r[7] = f2bf(hi.w);
    return r;
}

// ---------------------------------------------------------------------------
// Kernel 1: p[b][col] = HALF_DT * tanh(z0[b,:] . W[col,:] + bias[col])
// via bf16 MFMA with SPLIT-K: 128 blocks x 256 threads (4 waves).
//   wave = (khalf, half): batch half `half` (16 rows), K range
//   [khalf*256, khalf*256+256). 8-deep MFMA chain, 32 float4 loads/lane.
// khalf=1 waves dump partial acc to LDS; khalf=0 waves add, tanh, store.
// Fragment mapping (verified round 2): A lane l holds z0[half*16+(l&15)][k0+8*(l>>4)+j];
// B lane l holds W[col][k0+8*(l>>4)+j]; D lane l reg r -> batch 4*(l>>4)+r.
// Output p_ws[b][2048]; col 2047 never written (K2 forces it to 0).
// ---------------------------------------------------------------------------
__global__ __launch_bounds__(256) void v_mfma_kernel(
    const float* __restrict__ z0,    // (32, 512)
    const float* __restrict__ W,     // (2047, 512)
    const float* __restrict__ bias,  // (2047,)
    float* __restrict__ p_ws)        // (32, 2048)
{
    __shared__ float part[2][64][4];   // [half][lane][reg], 2 KB

    const int tid   = threadIdx.x;
    const int wave  = tid >> 6;
    const int lane  = tid & 63;
    const int half  = wave & 1;
    const int khalf = wave >> 1;
    const int m     = lane & 15;
    const int q     = lane >> 4;          // 0..3
    const int col   = blockIdx.x * 16 + m;
    const int wcol  = (col < 2046) ? col : 2046;   // clamp load row (store guarded)

    const float* zA = z0 + (half * 16 + m) * 512 + khalf * 256 + 8 * q;
    const float* wB = W + wcol * 512 + khalf * 256 + 8 * q;

    f32x4 acc = {0.f, 0.f, 0.f, 0.f};
    #pragma unroll 4
    for (int k0 = 0; k0 < 256; k0 += 32) {
        short8 a = cvt8(zA + k0);
        short8 b = cvt8(wB + k0);
        acc = __builtin_amdgcn_mfma_f32_16x16x32_bf16(a, b, acc, 0, 0, 0);
    }

    if (khalf == 1) {
        #pragma unroll
        for (int r = 0; r < 4; ++r) part[half][lane][r] = acc[r];
    }
    __syncthreads();
    if (khalf == 1) return;

    if (col < 2047) {
        const float bv = bias[col];
        #pragma unroll
        for (int r = 0; r < 4; ++r) {
            const int b = half * 16 + 4 * q + r;
            p_ws[b * 2048 + col] = HALF_DT * tanhf(acc[r] + part[half][lane][r] + bv);
        }
    }
}

// ---------------------------------------------------------------------------
// Kernel 2: x = h - 2*N h + 2*N^2 h  (truncated Neumann for (I+N)x = (I-N)h,
//   ||N||inf <= 0.01; truncation err <= 2*0.01^3*|h| ~ 1e-5, threshold 8.9e-2).
// (N u)[i] = p[i-1]*u[i-1] - p[i]*u[i+1]; p zero-padded outside [0,2046]
// enforces both physical boundaries exactly.
// Grid: 128 blocks = (batch) x (512-col quarter), halo +-4, 2 barriers.
// ---------------------------------------------------------------------------
__global__ __launch_bounds__(256) void solve2_kernel(
    const float* __restrict__ h,
    const float* __restrict__ p_ws,
    float* __restrict__ out)
{
    __shared__ float hl [520];   // h[g(c)], g(c) = cbase - 4 + c
    __shared__ float p_l[520];   // p[g(c)], 0 out of range
    __shared__ float u1l[520];

    const int b     = blockIdx.x >> 2;
    const int cbase = (blockIdx.x & 3) * 512;
    const int tid   = threadIdx.x;

    // stage 130 float4 quads (cols cbase-4 .. cbase+515), 0-padded
    if (tid < 130) {
        const int i0 = cbase - 4 + 4 * tid;
        float4 hv = make_float4(0.f, 0.f, 0.f, 0.f);
        float4 pv = make_float4(0.f, 0.f, 0.f, 0.f);
        if (i0 >= 0 && i0 + 3 < 2048) {
            hv = *reinterpret_cast<const float4*>(h    + b * 2048 + i0);
            pv = *reinterpret_cast<const float4*>(p_ws + b * 2048 + i0);
            if (i0 + 3 == 2047) pv.w = 0.f;   // p[2047] does not exist
        }
        *reinterpret_cast<float4*>(&hl [4 * tid]) = hv;
        *reinterpret_cast<float4*>(&p_l[4 * tid]) = pv;
    }
    __syncthreads();

    // pass 1: u1 = N h on c in [1, 518]
    for (int c = 1 + tid; c <= 518; c += 256)
        u1l[c] = p_l[c - 1] * hl[c - 1] - p_l[c] * hl[c + 1];
    __syncthreads();

    // pass 2: u2 = N u1; x = h - 2*(u1 - u2); store c in [4, 515]
    #pragma unroll
    for (int k = 0; k < 2; ++k) {
        const int c = 4 + tid + k * 256;
        const float u2 = p_l[c - 1] * u1l[c - 1] - p_l[c] * u1l[c + 1];
        out[b * 2048 + cbase + (c - 4)] = hl[c] - 2.f * (u1l[c] - u2);
    }
}

extern "C" void kernel_launch(void* const* d_in, const int* in_sizes, int n_in,
                              void* d_out, int out_size, void* d_ws, size_t ws_size,
                              hipStream_t stream) {
    const float* z0   = (const float*)d_in[0];   // (32, 512)
    const float* h    = (const float*)d_in[1];   // (32, 2048)
    const float* W    = (const float*)d_in[2];   // (2047, 512)
    const float* bias = (const float*)d_in[3];   // (2047,)
    float* out  = (float*)d_out;                 // (32, 2048)
    float* p_ws = (float*)d_ws;                  // (32, 2048) floats = 256 KB

    v_mfma_kernel<<<128, 256, 0, stream>>>(z0, W, bias, p_ws);
    solve2_kernel<<<128, 256, 0, stream>>>(h, p_ws, out);
}

// Round 6
// 12.239 us; speedup vs baseline: 1.4847x; 1.0217x over previous
//
#include <hip/hip_runtime.h>
#include <hip/hip_bf16.h>

#define HALF_DT 0.005f   // DT/2, DT = 0.01

typedef __attribute__((ext_vector_type(8))) short short8;   // 8 x bf16 (4 VGPRs)
typedef __attribute__((ext_vector_type(4))) float f32x4;    // MFMA accumulator

// fp32 -> bf16 via hardware cvt (compiler fuses pairs into v_cvt_pk_bf16_f32)
static __device__ inline short f2bf(float f) {
    __hip_bfloat16 b = __float2bfloat16(f);
    union { __hip_bfloat16 b; short s; } u; u.b = b;
    return u.s;
}

// two float4 (8 fp32) -> bf16x8 fragment
static __device__ inline short8 cvt8v(float4 lo, float4 hi) {
    short8 r;
    r[0] = f2bf(lo.x); r[1] = f2bf(lo.y); r[2] = f2bf(lo.z); r[3] = f2bf(lo.w);
    r[4] = f2bf(hi.x); r[5] = f2bf(hi.y); r[6] = f2bf(hi.z); r[7] = f2bf(hi.w);
    return r;
}

// tanh via single v_exp; saturates correctly (exp->inf => 1, exp->0 => -1)
static __device__ inline float fast_tanh(float x) {
    return 1.f - 2.f / (__expf(2.f * x) + 1.f);
}

// ---------------------------------------------------------------------------
// Kernel 1: p[b][col] = HALF_DT * tanh(z0[b,:] . W[col,:] + bias[col])
// bf16 MFMA, SPLIT-K: 128 blocks x 256 threads (4 waves = 2 khalf x 2 bhalf).
// ALL 32 float4 loads per lane are issued before the MFMA chain (single HBM
// latency exposure; W -- the cold 4.2 MB stream -- issued first).
// Fragment mapping (verified round 2). Output p_ws[b][2048]; col 2047 unwritten
// (K2 forces it to 0).
// ---------------------------------------------------------------------------
__global__ __launch_bounds__(256) void v_mfma_kernel(
    const float* __restrict__ z0,    // (32, 512)
    const float* __restrict__ W,     // (2047, 512)
    const float* __restrict__ bias,  // (2047,)
    float* __restrict__ p_ws)        // (32, 2048)
{
    __shared__ float part[2][64][4];   // [bhalf][lane][reg], 2 KB

    const int tid   = threadIdx.x;
    const int wave  = tid >> 6;
    const int lane  = tid & 63;
    const int half  = wave & 1;
    const int khalf = wave >> 1;
    const int m     = lane & 15;
    const int q     = lane >> 4;          // 0..3
    const int col   = blockIdx.x * 16 + m;
    const int wcol  = (col < 2046) ? col : 2046;   // clamp load row (store guarded)

    const float4* zA4 = reinterpret_cast<const float4*>(z0 + (half * 16 + m) * 512 + khalf * 256) + 2 * q;
    const float4* wB4 = reinterpret_cast<const float4*>(W + wcol * 512 + khalf * 256) + 2 * q;

    // ---- load phase: 16 W quads, then 16 z0 quads (stride 8 float4 = k+32) --
    float4 wraw[16], zraw[16];
    #pragma unroll
    for (int s = 0; s < 8; ++s) {
        wraw[2 * s]     = wB4[s * 8];
        wraw[2 * s + 1] = wB4[s * 8 + 1];
    }
    #pragma unroll
    for (int s = 0; s < 8; ++s) {
        zraw[2 * s]     = zA4[s * 8];
        zraw[2 * s + 1] = zA4[s * 8 + 1];
    }

    // ---- compute phase: convert + 8-deep MFMA chain ----
    f32x4 acc = {0.f, 0.f, 0.f, 0.f};
    #pragma unroll
    for (int s = 0; s < 8; ++s) {
        short8 a = cvt8v(zraw[2 * s], zraw[2 * s + 1]);
        short8 b = cvt8v(wraw[2 * s], wraw[2 * s + 1]);
        acc = __builtin_amdgcn_mfma_f32_16x16x32_bf16(a, b, acc, 0, 0, 0);
    }

    if (khalf == 1) {
        #pragma unroll
        for (int r = 0; r < 4; ++r) part[half][lane][r] = acc[r];
    }
    __syncthreads();
    if (khalf == 1) return;

    if (col < 2047) {
        const float bv = bias[col];
        #pragma unroll
        for (int r = 0; r < 4; ++r) {
            const int b = half * 16 + 4 * q + r;
            p_ws[b * 2048 + col] = HALF_DT * fast_tanh(acc[r] + part[half][lane][r] + bv);
        }
    }
}

// ---------------------------------------------------------------------------
// Kernel 2: x = h - 2*N h + 2*N^2 h  (truncated Neumann for (I+N)x = (I-N)h,
//   ||N||inf <= 0.01; truncation err <= 2e-5*|h|, threshold 8.9e-2).
// (N u)[i] = p[i-1]*u[i-1] - p[i]*u[i+1]; p zero-padded outside [0,2046]
// enforces both physical boundaries exactly.
// Grid: 256 blocks = (batch) x (256-col chunk), halo +-4, 2 barriers.
// Pass 2 is exactly one item per thread; staging one quad per active thread.
// ---------------------------------------------------------------------------
__global__ __launch_bounds__(256) void solve2_kernel(
    const float* __restrict__ h,
    const float* __restrict__ p_ws,
    float* __restrict__ out)
{
    __shared__ float hl [264];   // h[g(c)], g(c) = cbase - 4 + c
    __shared__ float p_l[264];   // p[g(c)], 0 out of range
    __shared__ float u1l[264];

    const int b     = blockIdx.x >> 3;
    const int cbase = (blockIdx.x & 7) * 256;
    const int tid   = threadIdx.x;

    // stage 66 float4 quads (cols cbase-4 .. cbase+259), 0-padded
    if (tid < 66) {
        const int i0 = cbase - 4 + 4 * tid;
        float4 hv = make_float4(0.f, 0.f, 0.f, 0.f);
        float4 pv = make_float4(0.f, 0.f, 0.f, 0.f);
        if (i0 >= 0 && i0 + 3 < 2048) {
            hv = *reinterpret_cast<const float4*>(h    + b * 2048 + i0);
            pv = *reinterpret_cast<const float4*>(p_ws + b * 2048 + i0);
            if (i0 + 3 == 2047) pv.w = 0.f;   // p[2047] does not exist
        }
        *reinterpret_cast<float4*>(&hl [4 * tid]) = hv;
        *reinterpret_cast<float4*>(&p_l[4 * tid]) = pv;
    }
    __syncthreads();

    // pass 1: u1 = N h on c in [1, 262] (2nd iteration active for tid<6 only)
    for (int c = 1 + tid; c <= 262; c += 256)
        u1l[c] = p_l[c - 1] * hl[c - 1] - p_l[c] * hl[c + 1];
    __syncthreads();

    // pass 2: u2 = N u1; x = h - 2*(u1 - u2); c = 4+tid covers [4, 259]
    {
        const int c = 4 + tid;
        const float u2 = p_l[c - 1] * u1l[c - 1] - p_l[c] * u1l[c + 1];
        out[b * 2048 + cbase + (c - 4)] = hl[c] - 2.f * (u1l[c] - u2);
    }
}

extern "C" void kernel_launch(void* const* d_in, const int* in_sizes, int n_in,
                              void* d_out, int out_size, void* d_ws, size_t ws_size,
                              hipStream_t stream) {
    const float* z0   = (const float*)d_in[0];   // (32, 512)
    const float* h    = (const float*)d_in[1];   // (32, 2048)
    const float* W    = (const float*)d_in[2];   // (2047, 512)
    const float* bias = (const float*)d_in[3];   // (2047,)
    float* out  = (float*)d_out;                 // (32, 2048)
    float* p_ws = (float*)d_ws;                  // (32, 2048) floats = 256 KB

    v_mfma_kernel<<<128, 256, 0, stream>>>(z0, W, bias, p_ws);
    solve2_kernel<<<256, 256, 0, stream>>>(h, p_ws, out);
}